// Round 8
// baseline (686.437 us; speedup 1.0000x reference)
//
#include <hip/hip_runtime.h>

// ---------------------------------------------------------------------------
// EncoderDecoder1DBlock on MI355X (gfx950).
// B=2, S=2048, D=1024, H=16, Dh=64, F=4096.
// f16 MFMA GEMMs (dbuf LDS + global_load_lds) + BARRIER-FREE MFMA flash
// attention: K/V fragments loaded directly from global (contiguous 16B),
// LDS only for the wave-private P transpose; keys split x2 by tile parity
// (fixed-max softmax => partials sum exactly), tiny combine kernel.
// ---------------------------------------------------------------------------

#define DEV __device__ __forceinline__

typedef __attribute__((ext_vector_type(8))) _Float16 half8;
typedef __attribute__((ext_vector_type(4))) _Float16 half4;
typedef __attribute__((ext_vector_type(2))) _Float16 half2v;
typedef __attribute__((ext_vector_type(4))) float    f32x4;

#define GLB(p) ((const __attribute__((address_space(1))) void*)(p))
#define LDS(p) ((__attribute__((address_space(3))) void*)(p))

DEV half2v pk(float a, float b) {
  return __builtin_bit_cast(half2v, __builtin_amdgcn_cvt_pkrtz(a, b));
}
DEV half4 pk4(float a, float b, float c, float d) {
  half2v lo = pk(a, b), hi = pk(c, d);
  half4 r; r.x = lo.x; r.y = lo.y; r.z = hi.x; r.w = hi.y;
  return r;
}

DEV float wave_sum_f(float v) {
  #pragma unroll
  for (int off = 32; off; off >>= 1) v += __shfl_xor(v, off);
  return v;
}

// ---------------------------------------------------------------------------
// Weight convert + transpose:  w [K,N] f32  ->  wt [N,K] f16
// ---------------------------------------------------------------------------
struct WtArgs { const float* w[8]; _Float16* wt[8]; };

__global__ __launch_bounds__(256) void wt_square(WtArgs a) {
  const float* w = a.w[blockIdx.z];
  _Float16* wt = a.wt[blockIdx.z];
  __shared__ float t[32][33];
  const int tx = threadIdx.x, ty = threadIdx.y;
  const int n0 = blockIdx.x * 32, k0 = blockIdx.y * 32;
  #pragma unroll
  for (int i = ty; i < 32; i += 8)
    t[i][tx] = w[(size_t)(k0 + i) * 1024 + n0 + tx];
  __syncthreads();
  #pragma unroll
  for (int i = ty; i < 32; i += 8)
    wt[(size_t)(n0 + i) * 1024 + k0 + tx] = (_Float16)t[tx][i];
}

__global__ __launch_bounds__(256) void wt_one(const float* __restrict__ w,
                                              _Float16* __restrict__ wt,
                                              int K, int N) {
  __shared__ float t[32][33];
  const int tx = threadIdx.x, ty = threadIdx.y;
  const int n0 = blockIdx.x * 32, k0 = blockIdx.y * 32;
  #pragma unroll
  for (int i = ty; i < 32; i += 8)
    t[i][tx] = w[(size_t)(k0 + i) * N + n0 + tx];
  __syncthreads();
  #pragma unroll
  for (int i = ty; i < 32; i += 8)
    wt[(size_t)(n0 + i) * K + k0 + tx] = (_Float16)t[tx][i];
}

__global__ __launch_bounds__(256) void cvt_f16(const float* __restrict__ in,
                                               _Float16* __restrict__ out) {
  const size_t i = ((size_t)blockIdx.x * 256 + threadIdx.x) * 4;
  const float4 v = *(const float4*)(in + i);
  *(half4*)(out + i) = pk4(v.x, v.y, v.z, v.w);
}

// ---------------------------------------------------------------------------
// LayerNorm over D=1024, one row per 256-thread block, f32 in -> f16 out
// ---------------------------------------------------------------------------
__global__ __launch_bounds__(256) void ln_kernel(const float* __restrict__ x,
                                                 const float* __restrict__ sc,
                                                 const float* __restrict__ bi,
                                                 _Float16* __restrict__ out) {
  const int row = blockIdx.x;
  const int t = threadIdx.x;
  const float4 v = ((const float4*)(x + (size_t)row * 1024))[t];
  float s  = v.x + v.y + v.z + v.w;
  float s2 = v.x * v.x + v.y * v.y + v.z * v.z + v.w * v.w;
  s = wave_sum_f(s); s2 = wave_sum_f(s2);
  __shared__ float red[8];
  const int lane = t & 63, wid = t >> 6;
  if (lane == 0) { red[wid] = s; red[4 + wid] = s2; }
  __syncthreads();
  s  = red[0] + red[1] + red[2] + red[3];
  s2 = red[4] + red[5] + red[6] + red[7];
  const float mean = s * (1.f / 1024.f);
  const float rstd = rsqrtf(s2 * (1.f / 1024.f) - mean * mean + 1e-6f);
  const float4 sv = ((const float4*)sc)[t];
  const float4 bv = ((const float4*)bi)[t];
  half4 o = pk4((v.x - mean) * rstd * sv.x + bv.x,
                (v.y - mean) * rstd * sv.y + bv.y,
                (v.z - mean) * rstd * sv.z + bv.z,
                (v.w - mean) * rstd * sv.w + bv.w);
  ((half4*)(out + (size_t)row * 1024))[t] = o;
}

// ---------------------------------------------------------------------------
// MFMA GEMM:  C[M,N] = A[M,K] @ B[K,N],  A f16 row-major, Bt = B^T f16 [N,K].
// BMxBN tile, BK per iter, 4 waves (2x2), double-buffered LDS, single
// barrier/iter with post-barrier global_load_lds staging.
// EPI: 1 = store f16, *scl for col<sclCols; 2 = +bias, ReLU, store f16;
//      3 = +resid(f32), store f32; 4 = +bias +resid(f32), store f32;
//      5 = like 1, but cols >= vcol0 are V: store TRANSPOSED per-head to
//          vt [B,H,64,S] (half4 along tokens), not to Cout.  S=2048 fixed.
// ---------------------------------------------------------------------------
template <int EPI, int BM, int BN, int BK>
__global__ __launch_bounds__(256)
void gemm_f16(const _Float16* __restrict__ A, const _Float16* __restrict__ Bt,
              void* __restrict__ Cout, const float* __restrict__ bias,
              const float* __restrict__ resid, int M, int N, int K,
              float scl, int sclCols, _Float16* __restrict__ vt, int vcol0) {
  constexpr int AM = BM / 32;
  constexpr int AN = BN / 32;
  constexpr int RA = BM * BK / 2048;
  constexpr int RB = BN * BK / 2048;
  constexpr int TPR = BK / 8;
  constexpr int RPR = 2048 / BK;
  __shared__ _Float16 As[2][BM * BK];
  __shared__ _Float16 Bs[2][BN * BK];
  const int tid = threadIdx.x;
  const int lane = tid & 63, wid = tid >> 6;
  const int wm = wid >> 1, wn = wid & 1;
  const int q = lane >> 4, m15 = lane & 15;
  const int bm = blockIdx.y, bn = blockIdx.x;

  const int trow = tid / TPR;
  const int tcol = (tid % TPR) * 8;
  const _Float16* Ab = A + ((size_t)bm * BM + trow) * K + tcol;
  const _Float16* Bb = Bt + ((size_t)bn * BN + trow) * K + tcol;

  f32x4 acc[AM][AN] = {};

  auto stage = [&](int k0, int buf) {
    #pragma unroll
    for (int r = 0; r < RA; r++)
      __builtin_amdgcn_global_load_lds(GLB(Ab + (size_t)r * RPR * K + k0),
                                       LDS(&As[buf][r * 2048 + wid * 512]), 16, 0, 0);
    #pragma unroll
    for (int r = 0; r < RB; r++)
      __builtin_amdgcn_global_load_lds(GLB(Bb + (size_t)r * RPR * K + k0),
                                       LDS(&Bs[buf][r * 2048 + wid * 512]), 16, 0, 0);
  };

  stage(0, 0);
  const int nit = K / BK;
  for (int it = 0; it < nit; it++) {
    const int buf = it & 1;
    __syncthreads();
    if (it + 1 < nit) stage((it + 1) * BK, buf ^ 1);
    #pragma unroll
    for (int kk = 0; kk < BK / 32; kk++) {
      half8 af[AM], bf[AN];
      #pragma unroll
      for (int i = 0; i < AM; i++)
        af[i] = *(const half8*)&As[buf][(wm * (BM / 2) + i * 16 + m15) * BK + kk * 32 + q * 8];
      #pragma unroll
      for (int i = 0; i < AN; i++)
        bf[i] = *(const half8*)&Bs[buf][(wn * (BN / 2) + i * 16 + m15) * BK + kk * 32 + q * 8];
      #pragma unroll
      for (int mi = 0; mi < AM; mi++)
        #pragma unroll
        for (int ni = 0; ni < AN; ni++)
          acc[mi][ni] = __builtin_amdgcn_mfma_f32_16x16x32_f16(af[mi], bf[ni],
                                                               acc[mi][ni], 0, 0, 0);
    }
  }

  const int rowbase = bm * BM + wm * (BM / 2);
  const int colbase = bn * BN + wn * (BN / 2);
  #pragma unroll
  for (int ni = 0; ni < AN; ni++) {
    const int col = colbase + ni * 16 + m15;
    float bv = 0.f;
    if (EPI == 2 || EPI == 4) bv = bias[col];
    const float cs = (EPI == 1 || EPI == 5) ? (col < sclCols ? scl : 1.f) : 1.f;
    if (EPI == 5 && col >= vcol0) {
      const int d = col & 63, hh = (col >> 6) & 15;
      #pragma unroll
      for (int mi = 0; mi < AM; mi++) {
        const int row = rowbase + mi * 16 + q * 4;
        const int bb = row >> 11, ss = row & 2047;  // S = 2048
        half4 ov = pk4(acc[mi][ni][0], acc[mi][ni][1],
                       acc[mi][ni][2], acc[mi][ni][3]);
        *(half4*)(vt + ((size_t)(bb * 16 + hh) * 64 + d) * 2048 + ss) = ov;
      }
      continue;
    }
    #pragma unroll
    for (int mi = 0; mi < AM; mi++) {
      #pragma unroll
      for (int r = 0; r < 4; r++) {
        const int row = rowbase + mi * 16 + q * 4 + r;
        const size_t idx = (size_t)row * N + col;
        float v = acc[mi][ni][r];
        if (EPI == 1 || EPI == 5) {
          ((_Float16*)Cout)[idx] = (_Float16)(v * cs);
        } else if (EPI == 2) {
          v += bv; v = v > 0.f ? v : 0.f;
          ((_Float16*)Cout)[idx] = (_Float16)v;
        } else if (EPI == 3) {
          ((float*)Cout)[idx] = v + resid[idx];
        } else {
          ((float*)Cout)[idx] = v + bv + resid[idx];
        }
      }
    }
  }
}

// ---------------------------------------------------------------------------
// BARRIER-FREE MFMA flash attention, fixed-max softmax (exp2 domain; see R4
// notes for validity), keys split x2 by KV-tile parity (blockIdx.z & 1).
// K fragments (A-op of S^T = K.Q^T) and V^T fragments (A-op of O^T = V^T.P^T)
// are contiguous 16B in global memory -> loaded directly, no staging, no
// __syncthreads. LDS holds only the wave-private P transpose.
// Outputs UNNORMALIZED O partial (f16) + softmax denominator l (f32);
// partials of the two splits sum exactly (fixed max).
// Q stride qs (pre-scaled by 0.125*log2e), K stride ks, Vt [B,H,64,Sk].
// Block: 128 threads = 2 waves x 32 q. grid (S/64, H, B*2).
// ---------------------------------------------------------------------------
__global__ __launch_bounds__(128)
void flash_attn(const _Float16* __restrict__ Q, int qs,
                const _Float16* __restrict__ Kp, int ks,
                const _Float16* __restrict__ Vt,
                _Float16* __restrict__ O0, _Float16* __restrict__ O1,
                float* __restrict__ l0, float* __restrict__ l1,
                int S, int Sk, int causal) {
  __shared__ _Float16 Pq[2][32 * 72];
  const int tid = threadIdx.x;
  const int lane = tid & 63, wid = tid >> 6;
  const int quad = lane >> 4, c15 = lane & 15;
  const int h = blockIdx.y;
  const int b = blockIdx.z >> 1, c = blockIdx.z & 1;
  _Float16* Op = c ? O1 : O0;
  float* lp = c ? l1 : l0;
  int qb = blockIdx.x;
  if (causal) qb = (qb & 1) ? ((int)gridDim.x - 1 - (qb >> 1)) : (qb >> 1);
  const int qw0 = qb * 64 + wid * 32;

  // Q B-fragments, held in registers for the whole kernel.
  half8 qf[2][2];
  #pragma unroll
  for (int nt = 0; nt < 2; nt++)
    #pragma unroll
    for (int kk = 0; kk < 2; kk++)
      qf[nt][kk] = *(const half8*)(Q + (size_t)(b * S + qw0 + nt * 16 + c15) * qs +
                                   h * 64 + kk * 32 + quad * 8);

  f32x4 oacc[4][2];
  #pragma unroll
  for (int i = 0; i < 4; i++)
    #pragma unroll
    for (int j = 0; j < 2; j++)
      oacc[i][j] = (f32x4){0.f, 0.f, 0.f, 0.f};
  float lpart[2] = {0.f, 0.f};

  const int tmax = causal ? qb : (Sk >> 6) - 1;
  const _Float16* Kg = Kp + (size_t)b * Sk * ks + h * 64;
  const _Float16* Vg = Vt + (size_t)(b * 16 + h) * 64 * Sk;

  for (int t = c; t <= tmax; t += 2) {
    const int jb = t * 64;

    // --- K fragments direct from global (16B contiguous per lane) ---
    half8 kf[4][2];
    #pragma unroll
    for (int mt = 0; mt < 4; mt++)
      #pragma unroll
      for (int kk = 0; kk < 2; kk++)
        kf[mt][kk] = *(const half8*)(Kg + (size_t)(jb + mt * 16 + c15) * ks +
                                     kk * 32 + quad * 8);

    // --- S^T = K . Q^T : C-layout (col=query c15, row=key quad*4+r)
    f32x4 s[4][2];
    #pragma unroll
    for (int mt = 0; mt < 4; mt++)
      #pragma unroll
      for (int nt = 0; nt < 2; nt++) {
        f32x4 z = {0.f, 0.f, 0.f, 0.f};
        z = __builtin_amdgcn_mfma_f32_16x16x32_f16(kf[mt][0], qf[nt][0], z, 0, 0, 0);
        z = __builtin_amdgcn_mfma_f32_16x16x32_f16(kf[mt][1], qf[nt][1], z, 0, 0, 0);
        s[mt][nt] = z;
      }

    // --- V^T fragments direct from global (contiguous along keys in Vt);
    //     issued now, consumed after softmax -> latency hidden by VALU.
    half8 vf[4][2];
    #pragma unroll
    for (int mtd = 0; mtd < 4; mtd++)
      #pragma unroll
      for (int kk = 0; kk < 2; kk++)
        vf[mtd][kk] = *(const half8*)(Vg + (size_t)(mtd * 16 + c15) * Sk +
                                      jb + kk * 32 + quad * 8);

    // --- causal mask (diagonal tiles only); exp2(-1e30) == 0 exactly ---
    if (causal && jb + 63 > qw0) {
      #pragma unroll
      for (int mt = 0; mt < 4; mt++)
        #pragma unroll
        for (int nt = 0; nt < 2; nt++) {
          const int qglob = qw0 + nt * 16 + c15;
          #pragma unroll
          for (int rr = 0; rr < 4; rr++) {
            const int kglob = jb + mt * 16 + quad * 4 + rr;
            if (kglob > qglob) s[mt][nt][rr] = -1e30f;
          }
        }
    }

    // --- fixed-max softmax: p = exp2(s), partial l, P -> wave-private LDS ---
    #pragma unroll
    for (int nt = 0; nt < 2; nt++) {
      float psum = 0.f;
      #pragma unroll
      for (int mt = 0; mt < 4; mt++) {
        #pragma unroll
        for (int rr = 0; rr < 4; rr++) {
          const float p = exp2f(s[mt][nt][rr]);
          s[mt][nt][rr] = p;
          psum += p;
        }
      }
      lpart[nt] += psum;
      #pragma unroll
      for (int mtk = 0; mtk < 4; mtk++) {
        *(half4*)&Pq[wid][(nt * 16 + c15) * 72 + mtk * 16 + quad * 4] =
            pk4(s[mtk][nt][0], s[mtk][nt][1], s[mtk][nt][2], s[mtk][nt][3]);
      }
    }

    // --- O^T += V^T . P^T  (P read back in B-operand layout; same wave,
    //     ordering enforced by lgkmcnt, no barrier needed) ---
    half8 pb[2][2];
    #pragma unroll
    for (int kk = 0; kk < 2; kk++)
      #pragma unroll
      for (int nt = 0; nt < 2; nt++)
        pb[kk][nt] = *(const half8*)&Pq[wid][(nt * 16 + c15) * 72 + kk * 32 + quad * 8];
    #pragma unroll
    for (int mtd = 0; mtd < 4; mtd++)
      #pragma unroll
      for (int nt = 0; nt < 2; nt++) {
        oacc[mtd][nt] = __builtin_amdgcn_mfma_f32_16x16x32_f16(vf[mtd][0], pb[0][nt],
                                                               oacc[mtd][nt], 0, 0, 0);
        oacc[mtd][nt] = __builtin_amdgcn_mfma_f32_16x16x32_f16(vf[mtd][1], pb[1][nt],
                                                               oacc[mtd][nt], 0, 0, 0);
      }
  }

  // --- epilogue: reduce l across quads; store UNNORMALIZED O + l ---
  #pragma unroll
  for (int nt = 0; nt < 2; nt++) {
    float l = lpart[nt];
    l += __shfl_xor(l, 16);
    l += __shfl_xor(l, 32);
    if (quad == 0)
      lp[(size_t)(b * S + qw0 + nt * 16 + c15) * 16 + h] = l;
    #pragma unroll
    for (int mtd = 0; mtd < 4; mtd++) {
      half4 ov = pk4(oacc[mtd][nt][0], oacc[mtd][nt][1],
                     oacc[mtd][nt][2], oacc[mtd][nt][3]);
      *(half4*)(Op + (size_t)(b * S + qw0 + nt * 16 + c15) * 1024 +
                h * 64 + mtd * 16 + quad * 4) = ov;
    }
  }
}

// ---------------------------------------------------------------------------
// Combine the two key-split partials: Out = (O0 + O1) / (l0 + l1).
// Writes to O1's buffer location via Out (safe: elementwise same index).
// ---------------------------------------------------------------------------
__global__ __launch_bounds__(256)
void attn_combine(const _Float16* __restrict__ O0, const _Float16* __restrict__ O1,
                  const float* __restrict__ l0, const float* __restrict__ l1,
                  _Float16* __restrict__ Out) {
  const size_t i = ((size_t)blockIdx.x * 256 + threadIdx.x) * 4;
  const size_t row = i >> 10;
  const int h = (int)((i >> 6) & 15);
  const float linv = 1.f / (l0[row * 16 + h] + l1[row * 16 + h]);
  half4 a = *(const half4*)(O0 + i);
  half4 b = *(const half4*)(O1 + i);
  *(half4*)(Out + i) = pk4(((float)a.x + (float)b.x) * linv,
                           ((float)a.y + (float)b.y) * linv,
                           ((float)a.z + (float)b.z) * linv,
                           ((float)a.w + (float)b.w) * linv);
}

// ---------------------------------------------------------------------------
// Host orchestration
// ---------------------------------------------------------------------------
extern "C" void kernel_launch(void* const* d_in, const int* in_sizes, int n_in,
                              void* d_out, int out_size, void* d_ws, size_t ws_size,
                              hipStream_t stream) {
  const float* targets = (const float*)d_in[0];
  const float* encoded = (const float*)d_in[1];
  const float* ln1_s = (const float*)d_in[2];
  const float* ln1_b = (const float*)d_in[3];
  const float* sa_wq = (const float*)d_in[4];
  const float* sa_wk = (const float*)d_in[5];
  const float* sa_wv = (const float*)d_in[6];
  const float* sa_wo = (const float*)d_in[7];
  const float* ln2_s = (const float*)d_in[8];
  const float* ln2_b = (const float*)d_in[9];
  const float* ca_wq = (const float*)d_in[10];
  const float* ca_wk = (const float*)d_in[11];
  const float* ca_wv = (const float*)d_in[12];
  const float* ca_wo = (const float*)d_in[13];
  const float* ln3_s = (const float*)d_in[14];
  const float* ln3_b = (const float*)d_in[15];
  const float* mlp_w1 = (const float*)d_in[16];
  const float* mlp_b1 = (const float*)d_in[17];
  const float* mlp_w2 = (const float*)d_in[18];
  const float* mlp_b2 = (const float*)d_in[19];

  const int B = 2, S = 2048, D = 1024, F = 4096, M = B * S;
  const size_t MB = 1024ull * 1024ull;
  const float QSCALE = 0.125f * 1.44269504f;  // 1/sqrt(64) * log2(e)
  char* ws = (char*)d_ws;
  _Float16* wsq   = (_Float16*)(ws);             // 8 x 1024^2 f16 = 16 MB
  _Float16* w1t   = (_Float16*)(ws + 16 * MB);   // [F,D] f16, 8 MB
  _Float16* w2t   = (_Float16*)(ws + 24 * MB);   // [D,F] f16, 8 MB
  _Float16* Abf   = (_Float16*)(ws + 32 * MB);   // LN output f16, 8 MB
  _Float16* encbf = (_Float16*)(ws + 40 * MB);   // encoded f16, 8 MB
  _Float16* QKV   = (_Float16*)(ws + 48 * MB);   // [M,3072] f16, 24 MB (48..72)
  _Float16* Qcb   = (_Float16*)(ws + 48 * MB);   // cross Q [M,1024], 8 MB
  _Float16* KVb   = (_Float16*)(ws + 56 * MB);   // cross KV [M,2048], 16 MB
  _Float16* h1    = (_Float16*)(ws + 48 * MB);   // [M,F] f16, 32 MB (48..80)
  _Float16* Op0   = (_Float16*)(ws + 72 * MB);   // attn split-0 partial, 8 MB
  _Float16* Vtb   = (_Float16*)(ws + 80 * MB);   // V^T [B,H,64,S], 8 MB
  _Float16* Aob   = (_Float16*)(ws + 88 * MB);   // split-1 partial & attn out, 8 MB
  float*    xres  = (float*)(ws + 96 * MB);      // 16 MB
  float*    yres  = (float*)(ws + 112 * MB);     // 16 MB
  // l partials (2 x 256 KB) live in regions whose real contents are written
  // only AFTER the corresponding combine: self -> xres region, cross -> yres.
  float* lse0 = (float*)(ws + 96 * MB);
  float* lse1 = (float*)(ws + 96 * MB + 256 * 1024);
  float* lce0 = (float*)(ws + 112 * MB);
  float* lce1 = (float*)(ws + 112 * MB + 256 * 1024);

  {
    WtArgs wa;
    const float* sw[8] = {sa_wq, sa_wk, sa_wv, sa_wo, ca_wq, ca_wk, ca_wv, ca_wo};
    for (int i = 0; i < 8; i++) { wa.w[i] = sw[i]; wa.wt[i] = wsq + (size_t)i * D * D; }
    wt_square<<<dim3(32, 32, 8), dim3(32, 8), 0, stream>>>(wa);
  }
  wt_one<<<dim3(F / 32, D / 32), dim3(32, 8), 0, stream>>>(mlp_w1, w1t, D, F);
  wt_one<<<dim3(D / 32, F / 32), dim3(32, 8), 0, stream>>>(mlp_w2, w2t, F, D);
  cvt_f16<<<(M * D) / 1024, 256, 0, stream>>>(encoded, encbf);

  const dim3 gA(S / 64, 16, B * 2);      // flash: 2 waves x 32q, key-split x2
  const int gC = (M * D) / 1024;         // combine blocks

  // --- self-attention block (fused QKV; V^T emitted by GEMM epilogue) ---
  ln_kernel<<<M, 256, 0, stream>>>(targets, ln1_s, ln1_b, Abf);
  gemm_f16<5, 128, 128, 32><<<dim3(3072 / 128, M / 128), 256, 0, stream>>>(
      Abf, wsq, QKV, nullptr, nullptr, M, 3072, D, QSCALE, 1024, Vtb, 2048);
  flash_attn<<<gA, 128, 0, stream>>>(QKV, 3072, QKV + 1024, 3072, Vtb,
                                     Op0, Aob, lse0, lse1, S, S, 1);
  attn_combine<<<gC, 256, 0, stream>>>(Op0, Aob, lse0, lse1, Aob);
  gemm_f16<3, 64, 64, 64><<<dim3(1024 / 64, M / 64), 256, 0, stream>>>(
      Aob, wsq + 3ull * D * D, xres, nullptr, targets, M, D, D, 1.f, 0, nullptr, 0);

  // --- cross-attention block (fused KV; V^T emitted by GEMM epilogue) ---
  ln_kernel<<<M, 256, 0, stream>>>(xres, ln2_s, ln2_b, Abf);
  gemm_f16<1, 64, 64, 64><<<dim3(1024 / 64, M / 64), 256, 0, stream>>>(
      Abf, wsq + 4ull * D * D, Qcb, nullptr, nullptr, M, D, D, QSCALE, 1024, nullptr, 0);
  gemm_f16<5, 64, 128, 32><<<dim3(2048 / 128, M / 64), 256, 0, stream>>>(
      encbf, wsq + 5ull * D * D, KVb, nullptr, nullptr, M, 2048, D, 1.f, 0, Vtb, 1024);
  flash_attn<<<gA, 128, 0, stream>>>(Qcb, 1024, KVb, 2048, Vtb,
                                     Op0, Aob, lce0, lce1, S, S, 0);
  attn_combine<<<gC, 256, 0, stream>>>(Op0, Aob, lce0, lce1, Aob);
  gemm_f16<3, 64, 64, 64><<<dim3(1024 / 64, M / 64), 256, 0, stream>>>(
      Aob, wsq + 7ull * D * D, yres, nullptr, xres, M, D, D, 1.f, 0, nullptr, 0);

  // --- MLP block ---
  ln_kernel<<<M, 256, 0, stream>>>(yres, ln3_s, ln3_b, Abf);
  gemm_f16<2, 128, 128, 32><<<dim3(F / 128, M / 128), 256, 0, stream>>>(
      Abf, w1t, h1, mlp_b1, nullptr, M, F, D, 1.f, 0, nullptr, 0);
  gemm_f16<4, 128, 64, 64><<<dim3(1024 / 64, M / 128), 256, 0, stream>>>(
      h1, w2t, (float*)d_out, mlp_b2, yres, M, D, F, 1.f, 0, nullptr, 0);

  (void)in_sizes; (void)n_in; (void)out_size; (void)ws_size;
}